// Round 1
// baseline (2473.315 us; speedup 1.0000x reference)
//
#include <hip/hip_runtime.h>
#include <hip/hip_bf16.h>
#include <math.h>

#define NROWS 131072
#define ACT_D 12
#define COND_D 256
#define KEMB 256
#define EDIM 16
#define H1D 512
#define H2D 256
#define NB 16384

// ---------------------------------------------------------------------------
// ws layout (float offsets):
//   wsA @ 0         : 67108864 floats (268MB)  h1 -> (first half) distT -> d2out
//   wsB @ 67108864  : 33554432 floats (134MB)  h2 -> d1out
//   counts @ 100663296 : 256 ints
//   stats  @ 100663552 : 256*6 ints
//   acc    @ 100665088 : [0]=qsum  [1]=contra_sum  [2]=recon_sum
// total ~403 MB
// ---------------------------------------------------------------------------

__global__ void init_kernel(int* counts, float* acc) {
    int t = threadIdx.x;
    counts[t] = 0;
    if (t < 3) acc[t] = 0.0f;
}

// ---------------------------------------------------------------------------
// fp32 tiled GEMM + bias + ELU.  C[M,Nw] = elu(A[M,Kd] @ W[Kd,Nw] + bias)
// CONCAT>0: logical A row = concat(A[row,0:CONCAT] (stride CONCAT),
//                                  A2[row,0:Kd-CONCAT] (stride COND_D))
// BM=BN=128, BK=16, 256 threads, 8x8 micro-tile.
// ---------------------------------------------------------------------------
template<int CONCAT>
__global__ __launch_bounds__(256)
void gemm_elu_kernel(const float* __restrict__ A, const float* __restrict__ A2,
                     const float* __restrict__ W, const float* __restrict__ bias,
                     float* __restrict__ C, int M, int Nw, int Kd)
{
    const int BK = 16, BMP = 132;
    __shared__ float As[BK][BMP];   // [k][m]
    __shared__ float Bs[BK][BMP];   // [k][n] (only 128 cols used)
    int tid = threadIdx.x;
    int mg = tid & 15, ng = tid >> 4;
    long rowBase = (long)blockIdx.x * 128;
    int  colBase = blockIdx.y * 128;

    float acc[8][8];
#pragma unroll
    for (int i = 0; i < 8; ++i)
#pragma unroll
        for (int j = 0; j < 8; ++j) acc[i][j] = 0.0f;

    int ar = tid >> 2;           // 0..63
    int ac = (tid & 3) * 4;      // 0,4,8,12
    int wk = tid >> 5;           // 0..7
    int wn = (tid & 31) * 4;     // 0..124

    int kTiles = (Kd + BK - 1) / BK;
    for (int t = 0; t < kTiles; ++t) {
        int k0 = t * BK;
#pragma unroll
        for (int it = 0; it < 2; ++it) {
            int r = it * 64 + ar;
            int gk = k0 + ac;
            float4 v = make_float4(0.f, 0.f, 0.f, 0.f);
            long grow = rowBase + r;
            if (CONCAT > 0) {
                if (gk + 3 < Kd) {
                    if (gk < CONCAT) v = *(const float4*)(A + grow * CONCAT + gk);
                    else             v = *(const float4*)(A2 + grow * COND_D + (gk - CONCAT));
                }
            } else {
                if (gk < Kd) v = *(const float4*)(A + grow * (long)Kd + gk);
            }
            As[ac + 0][r] = v.x; As[ac + 1][r] = v.y;
            As[ac + 2][r] = v.z; As[ac + 3][r] = v.w;
        }
#pragma unroll
        for (int it = 0; it < 2; ++it) {
            int k = it * 8 + wk;
            int gk = k0 + k;
            float4 v = make_float4(0.f, 0.f, 0.f, 0.f);
            if (gk < Kd) v = *(const float4*)(W + (long)gk * Nw + colBase + wn);
            *(float4*)&Bs[k][wn] = v;
        }
        __syncthreads();
#pragma unroll
        for (int k = 0; k < BK; ++k) {
            float af[8], bf[8];
            *(float4*)&af[0] = *(const float4*)&As[k][mg * 8];
            *(float4*)&af[4] = *(const float4*)&As[k][mg * 8 + 4];
            *(float4*)&bf[0] = *(const float4*)&Bs[k][ng * 8];
            *(float4*)&bf[4] = *(const float4*)&Bs[k][ng * 8 + 4];
#pragma unroll
            for (int i = 0; i < 8; ++i)
#pragma unroll
                for (int j = 0; j < 8; ++j)
                    acc[i][j] += af[i] * bf[j];
        }
        __syncthreads();
    }

    float bv[8];
#pragma unroll
    for (int j = 0; j < 8; ++j) bv[j] = bias[colBase + ng * 8 + j];
#pragma unroll
    for (int i = 0; i < 8; ++i) {
        long grow = rowBase + mg * 8 + i;
        float o[8];
#pragma unroll
        for (int j = 0; j < 8; ++j) {
            float x = acc[i][j] + bv[j];
            o[j] = x > 0.0f ? x : (expf(x) - 1.0f);   // ELU
        }
        *(float4*)(C + grow * Nw + colBase + ng * 8)     = *(float4*)&o[0];
        *(float4*)(C + grow * Nw + colBase + ng * 8 + 4) = *(float4*)&o[4];
    }
}

// ---------------------------------------------------------------------------
// K3: z = h2@W3+b3, normalize, distances vs normalized embedding, argmax,
// quantized -> d_out, q-latent partial, counts, distT (transposed) write.
// 16 rows / block, 256 threads.
// ---------------------------------------------------------------------------
__global__ __launch_bounds__(256)
void quantize_kernel(const float* __restrict__ h2, const float* __restrict__ W3,
                     const float* __restrict__ b3, const float* __restrict__ emb,
                     float* __restrict__ distT, float* __restrict__ outQ,
                     float* __restrict__ outIdx, int* __restrict__ counts,
                     float* __restrict__ qsum)
{
    __shared__ float h2t[16 * 260];   // [r][j] stride 260
    __shared__ float w3t[16 * 260];   // transposed: [c][j] stride 260
    __shared__ float nwt[256 * 20];   // normalized embedding [k][e] stride 20
    __shared__ float zt[16 * 17];     // normalized z [r][e]
    __shared__ float dt[16 * 257];    // distances [r][k]
    __shared__ int   lcnt[256];
    __shared__ float swred[4];

    int t = threadIdx.x;
    long rowBase = (long)blockIdx.x * 16;

    for (int it = 0; it < 16; ++it)
        h2t[it * 260 + t] = h2[(rowBase + it) * 256 + t];
    for (int it = 0; it < 16; ++it) {
        int flat = it * 256 + t;              // 0..4095 = j*16+c
        int j = flat >> 4, c = flat & 15;
        w3t[c * 260 + j] = W3[flat];
    }
    {
        float e0[16]; float ss = 0.f;
#pragma unroll
        for (int i = 0; i < 16; ++i) { e0[i] = emb[t * 16 + i]; ss += e0[i] * e0[i]; }
        float inv = 1.0f / fmaxf(sqrtf(ss), 1e-12f);
#pragma unroll
        for (int i = 0; i < 16; ++i) nwt[t * 20 + i] = e0[i] * inv;
    }
    lcnt[t] = 0;
    __syncthreads();

    int r = t >> 4, c = t & 15;
    // z[r][c]
    float zacc = b3[c];
    for (int j4 = 0; j4 < 64; ++j4) {
        float4 h = *(const float4*)&h2t[r * 260 + j4 * 4];
        float4 w = *(const float4*)&w3t[c * 260 + j4 * 4];
        zacc += h.x * w.x + h.y * w.y + h.z * w.z + h.w * w.w;
    }
    float ss = zacc * zacc;
#pragma unroll
    for (int m = 1; m < 16; m <<= 1) ss += __shfl_xor(ss, m, 64);
    zt[r * 17 + c] = zacc / fmaxf(sqrtf(ss), 1e-12f);
    __syncthreads();

    float zr[16];
#pragma unroll
    for (int e = 0; e < 16; ++e) zr[e] = zt[r * 17 + e];
    float best = -1e30f; int bidx = 0;
    for (int cc = 0; cc < 16; ++cc) {
        int col = cc * 16 + c;               // this thread covers cols == c (mod 16)
        float d = 0.f;
#pragma unroll
        for (int e4 = 0; e4 < 4; ++e4) {
            float4 w = *(const float4*)&nwt[col * 20 + e4 * 4];
            d += zr[e4 * 4 + 0] * w.x + zr[e4 * 4 + 1] * w.y
               + zr[e4 * 4 + 2] * w.z + zr[e4 * 4 + 3] * w.w;
        }
        dt[r * 257 + col] = d;
        if (d > best || (d == best && col < bidx)) { best = d; bidx = col; }
    }
    // merge argmax across the 16 lanes of row r (ties -> smallest index, numpy)
#pragma unroll
    for (int m = 1; m < 16; m <<= 1) {
        float ov = __shfl_xor(best, m, 64);
        int   oi = __shfl_xor(bidx, m, 64);
        if (ov > best || (ov == best && oi < bidx)) { best = ov; bidx = oi; }
    }

    float q = emb[bidx * 16 + c];
    outQ[(rowBase + r) * 16 + c] = q;        // quantized_st == quantized (fwd)
    float df = q - zacc;
    float part = df * df;
#pragma unroll
    for (int m = 1; m < 64; m <<= 1) part += __shfl_xor(part, m, 64);
    if ((t & 63) == 0) swred[t >> 6] = part;
    if (c == 0) {
        outIdx[rowBase + r] = (float)bidx;
        atomicAdd(&lcnt[bidx], 1);
    }
    __syncthreads();
    if (t == 0) atomicAdd(qsum, swred[0] + swred[1] + swred[2] + swred[3]);
    if (lcnt[t] > 0) atomicAdd(&counts[t], lcnt[t]);

    // transposed distance write: lanes 0..15 -> consecutive rows of one column
    int rr = t & 15, cg = t >> 4;
    for (int i = 0; i < 16; ++i) {
        int col = i * 16 + cg;
        distT[(long)col * NROWS + rowBase + rr] = dt[rr * 257 + col];
    }
}

// ---------------------------------------------------------------------------
// SelA: per-column histogram over [-1,1], find median bin (65536th) and
// top-512 threshold bin.  One block per column.
// ---------------------------------------------------------------------------
__global__ __launch_bounds__(256)
void selA_kernel(const float* __restrict__ distT, int* __restrict__ stats)
{
    __shared__ int hist[NB];
    __shared__ int part[256];
    int t = threadIdx.x, c = blockIdx.x;
    for (int i = t; i < NB; i += 256) hist[i] = 0;
    __syncthreads();
    const float* col = distT + (long)c * NROWS;
    for (int i = t; i < NROWS; i += 256) {
        float v = col[i];
        int b = (int)((v + 1.0f) * (NB * 0.5f));
        b = min(max(b, 0), NB - 1);
        atomicAdd(&hist[b], 1);
    }
    __syncthreads();
    int s = 0;
    for (int i = 0; i < NB / 256; ++i) s += hist[t * (NB / 256) + i];
    part[t] = s;
    __syncthreads();
    if (t == 0) {
        // median (65536th smallest, i.e. count of bottom half)
        int target = NROWS / 2;
        int cum = 0; int chunk = 0;
        while (cum + part[chunk] < target) { cum += part[chunk]; ++chunk; }
        int b = chunk * (NB / 256);
        while (cum + hist[b] < target) { cum += hist[b]; ++b; }
        int medBin = b, needLow = target - cum, cntMed = hist[b];
        // top-512 threshold
        int cumA = 0; chunk = 255;
        while (cumA + part[chunk] < 512) { cumA += part[chunk]; --chunk; }
        b = chunk * (NB / 256) + (NB / 256) - 1;
        while (cumA + hist[b] < 512) { cumA += hist[b]; --b; }
        int topBin = b, needTop = 512 - cumA, cntTop = hist[b];
        int* st = stats + c * 6;
        st[0] = medBin; st[1] = needLow; st[2] = cntMed;
        st[3] = topBin; st[4] = needTop; st[5] = cntTop;
    }
}

// ---------------------------------------------------------------------------
// SelB: re-scan column; top-512 mean (dis_pos) and logsumexp over bottom half.
// contra_col = log1p( S * exp((mUp - dis_pos)/0.07) )   (permutation-invariant)
// ---------------------------------------------------------------------------
__global__ __launch_bounds__(256)
void selB_kernel(const float* __restrict__ distT, const int* __restrict__ stats,
                 float* __restrict__ contra_sum)
{
    __shared__ float red[16];   // [wave][quantity]
    int t = threadIdx.x, c = blockIdx.x;
    const int* st = stats + c * 6;
    int medBin = st[0], needLow = st[1], cntMed = st[2];
    int topBin = st[3], needTop = st[4], cntTop = st[5];
    const float binw = 2.0f / NB;
    float mUp = -1.0f + (medBin + 1) * binw;
    const float INVT = 1.0f / 0.07f;
    const float* col = distT + (long)c * NROWS;
    float topS = 0.f, tbS = 0.f, lowS = 0.f, mbS = 0.f;
    for (int i = t; i < NROWS; i += 256) {
        float v = col[i];
        int b = (int)((v + 1.0f) * (NB * 0.5f));
        b = min(max(b, 0), NB - 1);
        if (b > topBin)       topS += v;
        else if (b == topBin) tbS += v;
        if (b < medBin)       lowS += expf((v - mUp) * INVT);
        else if (b == medBin) mbS  += expf((v - mUp) * INVT);
    }
#pragma unroll
    for (int m = 1; m < 64; m <<= 1) {
        topS += __shfl_xor(topS, m, 64);
        tbS  += __shfl_xor(tbS, m, 64);
        lowS += __shfl_xor(lowS, m, 64);
        mbS  += __shfl_xor(mbS, m, 64);
    }
    if ((t & 63) == 0) {
        int w = t >> 6;
        red[w * 4 + 0] = topS; red[w * 4 + 1] = tbS;
        red[w * 4 + 2] = lowS; red[w * 4 + 3] = mbS;
    }
    __syncthreads();
    if (t == 0) {
        float T0 = 0, T1 = 0, T2 = 0, T3 = 0;
        for (int w = 0; w < 4; ++w) {
            T0 += red[w * 4 + 0]; T1 += red[w * 4 + 1];
            T2 += red[w * 4 + 2]; T3 += red[w * 4 + 3];
        }
        float dis_pos = (T0 + needTop * (T1 / cntTop)) * (1.0f / 512.0f);
        float S = T2 + needLow * (T3 / cntMed);
        float colContra = log1pf(S * expf((mUp - dis_pos) * INVT));
        atomicAdd(contra_sum, colContra);
    }
}

// ---------------------------------------------------------------------------
// D3: reconstructed = d2 @ dec_w3 + b, + reconstruction-loss partial.
// 16 rows / block.
// ---------------------------------------------------------------------------
__global__ __launch_bounds__(256)
void dec3_kernel(const float* __restrict__ d2, const float* __restrict__ W,
                 const float* __restrict__ bias, const float* __restrict__ actions,
                 float* __restrict__ rec, float* __restrict__ recon_sum)
{
    __shared__ float dtile[16 * 516];
    __shared__ float wt[512 * 12];
    __shared__ float red2[4];
    int t = threadIdx.x;
    long rowBase = (long)blockIdx.x * 16;
    for (int it = 0; it < 24; ++it) wt[it * 256 + t] = W[it * 256 + t];
    for (int it = 0; it < 32; ++it) {
        int flat = it * 256 + t;
        int r = flat >> 9, k = flat & 511;
        dtile[r * 516 + k] = d2[(rowBase + r) * 512 + k];
    }
    __syncthreads();
    float part = 0.f;
    if (t < 192) {
        int r = t / 12, cc = t % 12;
        float acc = bias[cc];
        for (int k4 = 0; k4 < 128; ++k4) {
            float4 h = *(const float4*)&dtile[r * 516 + k4 * 4];
            acc += h.x * wt[(k4 * 4 + 0) * 12 + cc] + h.y * wt[(k4 * 4 + 1) * 12 + cc]
                 + h.z * wt[(k4 * 4 + 2) * 12 + cc] + h.w * wt[(k4 * 4 + 3) * 12 + cc];
        }
        rec[(rowBase + r) * 12 + cc] = acc;
        float df = acc - actions[(rowBase + r) * 12 + cc];
        part = df * df;
    }
#pragma unroll
    for (int m = 1; m < 64; m <<= 1) part += __shfl_xor(part, m, 64);
    if ((t & 63) == 0) red2[t >> 6] = part;
    __syncthreads();
    if (t == 0) atomicAdd(recon_sum, red2[0] + red2[1] + red2[2] + red2[3]);
}

// ---------------------------------------------------------------------------
// finalize: perplexity from counts + scalar outputs.
// ---------------------------------------------------------------------------
__global__ void finalize_kernel(const int* __restrict__ counts,
                                const float* __restrict__ acc,
                                float* __restrict__ outScal)
{
    __shared__ float red[4];
    int t = threadIdx.x;
    float p = counts[t] * (1.0f / NROWS);
    float term = p * logf(p + 1e-10f);
#pragma unroll
    for (int m = 1; m < 64; m <<= 1) term += __shfl_xor(term, m, 64);
    if ((t & 63) == 0) red[t >> 6] = term;
    __syncthreads();
    if (t == 0) {
        float hsum = red[0] + red[1] + red[2] + red[3];
        float ql = acc[0] * (1.0f / (NROWS * 16.0f));
        outScal[0] = ql;                               // q_latent_loss
        outScal[1] = 0.25f * ql;                       // e_latent_loss (COMMIT * mean)
        outScal[2] = acc[1] * (1.0f / 256.0f);         // contra_loss
        outScal[3] = expf(-hsum);                      // perplexity
        outScal[4] = acc[2] * (1.0f / (NROWS * 12.0f));// reconstruction_loss
    }
}

extern "C" void kernel_launch(void* const* d_in, const int* in_sizes, int n_in,
                              void* d_out, int out_size, void* d_ws, size_t ws_size,
                              hipStream_t stream)
{
    const float* actions    = (const float*)d_in[0];
    const float* conditions = (const float*)d_in[1];
    const float* enc_w1 = (const float*)d_in[2];
    const float* enc_b1 = (const float*)d_in[3];
    const float* enc_w2 = (const float*)d_in[4];
    const float* enc_b2 = (const float*)d_in[5];
    const float* enc_w3 = (const float*)d_in[6];
    const float* enc_b3 = (const float*)d_in[7];
    const float* dec_w1 = (const float*)d_in[8];
    const float* dec_b1 = (const float*)d_in[9];
    const float* dec_w2 = (const float*)d_in[10];
    const float* dec_b2 = (const float*)d_in[11];
    const float* dec_w3 = (const float*)d_in[12];
    const float* dec_b3 = (const float*)d_in[13];
    const float* emb    = (const float*)d_in[14];

    float* out    = (float*)d_out;
    float* outRec  = out;                        // N*12
    float* outQ    = out + (long)NROWS * 12;     // N*16
    float* outIdx  = out + (long)NROWS * 28;     // N (idx as float)
    float* outScal = out + (long)NROWS * 29;     // 5 scalars

    float* ws  = (float*)d_ws;
    float* wsA = ws;                             // h1 / distT / d2out
    float* wsB = ws + 67108864;                  // h2 / d1out
    int*   counts = (int*)(ws + 100663296);
    int*   stats  = (int*)(ws + 100663552);
    float* acc    = ws + 100665088;              // qsum, contra_sum, recon_sum

    hipLaunchKernelGGL(init_kernel, dim3(1), dim3(256), 0, stream, counts, acc);
    // E1: h1 = elu(concat(actions,conditions) @ enc_w1 + b1)
    hipLaunchKernelGGL((gemm_elu_kernel<ACT_D>), dim3(1024, 4), dim3(256), 0, stream,
                       actions, conditions, enc_w1, enc_b1, wsA, NROWS, H1D, ACT_D + COND_D);
    // E2: h2 = elu(h1 @ enc_w2 + b2)
    hipLaunchKernelGGL((gemm_elu_kernel<0>), dim3(1024, 2), dim3(256), 0, stream,
                       wsA, (const float*)nullptr, enc_w2, enc_b2, wsB, NROWS, H2D, H1D);
    // K3: z, normalize, argmax, quantized, counts, q-latent, distT
    hipLaunchKernelGGL(quantize_kernel, dim3(8192), dim3(256), 0, stream,
                       wsB, enc_w3, enc_b3, emb, wsA, outQ, outIdx, counts, &acc[0]);
    // contra-loss selection (replaces full column sort)
    hipLaunchKernelGGL(selA_kernel, dim3(256), dim3(256), 0, stream, wsA, stats);
    hipLaunchKernelGGL(selB_kernel, dim3(256), dim3(256), 0, stream, wsA, stats, &acc[1]);
    // D1: d1 = elu(concat(quantized,conditions) @ dec_w1 + b1)
    hipLaunchKernelGGL((gemm_elu_kernel<EDIM>), dim3(1024, 2), dim3(256), 0, stream,
                       outQ, conditions, dec_w1, dec_b1, wsB, NROWS, H2D, EDIM + COND_D);
    // D2: d2 = elu(d1 @ dec_w2 + b2)
    hipLaunchKernelGGL((gemm_elu_kernel<0>), dim3(1024, 4), dim3(256), 0, stream,
                       wsB, (const float*)nullptr, dec_w2, dec_b2, wsA, NROWS, H1D, H2D);
    // D3: reconstructed + loss
    hipLaunchKernelGGL(dec3_kernel, dim3(8192), dim3(256), 0, stream,
                       wsA, dec_w3, dec_b3, actions, outRec, &acc[2]);
    // scalars
    hipLaunchKernelGGL(finalize_kernel, dim3(1), dim3(256), 0, stream, counts, acc, outScal);
}